// Round 9
// baseline (410.493 us; speedup 1.0000x reference)
//
#include <hip/hip_runtime.h>

// Problem constants (fixed by reference): B=128, L=256, F=P=4, IN=1024, H=256, C=7
#define NN 32768        // N = B*L
#define INF 1024
#define HF 256

typedef __bf16 bf16x8 __attribute__((ext_vector_type(8)));
typedef float f32x4 __attribute__((ext_vector_type(4)));
typedef unsigned short u16x8 __attribute__((ext_vector_type(8)));

__device__ __forceinline__ float bf2f(unsigned short u) {
  union { unsigned int i; float f; } v; v.i = ((unsigned int)u) << 16; return v.f;
}
__device__ __forceinline__ unsigned short f2bf(float f) {
  union { float f; unsigned int i; } v; v.f = f;
  unsigned int x = v.i;
  return (unsigned short)((x + 0x7fffu + ((x >> 16) & 1u)) >> 16);  // RNE
}

// async global->LDS, 16B per lane; dest = lds base (wave-uniform) + lane*16
__device__ __forceinline__ void ld_lds16(const unsigned short* g, unsigned short* l) {
  __builtin_amdgcn_global_load_lds(
      (__attribute__((address_space(1))) const unsigned int*)g,
      (__attribute__((address_space(3))) unsigned int*)l, 16, 0, 0);
}

// ---- prep:
//  blocks [0,16384):        x fp32 -> bf16, one-shot, 32B read / 16B write per thread
//  blocks [16384,16384+288): weight repack via 64x64 LDS transpose
// WbigT[n][k] (1024x1024) = [W0|W1|Wroot|Wskip]^T ; WsmT[n][k] (256x512) = [Wgrt;Wrel]^T
__global__ __launch_bounds__(256)
void diagcn_prep(const float* __restrict__ x, const float* __restrict__ Wrgcn,
                 const float* __restrict__ Wroot, const float* __restrict__ Wskip,
                 const float* __restrict__ Wgrt, const float* __restrict__ Wrel,
                 unsigned short* __restrict__ Xbf, unsigned short* __restrict__ WbigT,
                 unsigned short* __restrict__ WsmT, float* __restrict__ loss) {
  int bid = blockIdx.x;
  if (bid < 16384) {
    if (bid == 0 && threadIdx.x == 0) loss[0] = 0.f;
    int gid = bid * 256 + threadIdx.x;          // 4,194,304 threads, 8 floats each
    const float4* xv = (const float4*)x;
    float4 a = xv[2 * gid], b2 = xv[2 * gid + 1];
    u16x8 o;
    o[0] = f2bf(a.x); o[1] = f2bf(a.y); o[2] = f2bf(a.z); o[3] = f2bf(a.w);
    o[4] = f2bf(b2.x); o[5] = f2bf(b2.y); o[6] = f2bf(b2.z); o[7] = f2bf(b2.w);
    *(u16x8*)&Xbf[(size_t)gid * 8] = o;
    return;
  }
  __shared__ float tile[64 * 65];
  int tb = bid - 16384;
  const float* src;
  int k0, ncol0;
  unsigned short* dst;
  int ldd, nrow0;
  if (tb < 256) {            // WbigT tiles: tn 0..15, tk 0..15
    int tn = tb >> 4, tk = tb & 15;
    int mat = tn >> 2;
    src = (mat == 0) ? Wrgcn : (mat == 1) ? (Wrgcn + 262144) : (mat == 2) ? Wroot : Wskip;
    k0 = tk * 64; ncol0 = (tn & 3) * 64;
    dst = WbigT; ldd = 1024; nrow0 = tn * 64;
  } else {                   // WsmT tiles: tn 0..3, tk 0..7
    int t2 = tb - 256;
    int tn = t2 >> 3, tk = t2 & 7;
    src = (tk < 4) ? Wgrt : Wrel;
    k0 = (tk & 3) * 64; ncol0 = tn * 64;
    dst = WsmT; ldd = 512; nrow0 = tn * 64;
  }
  int kdst0 = (tb < 256) ? k0 : (((tb - 256) & 7) * 64);
  int c = threadIdx.x & 63, rb = threadIdx.x >> 6;
#pragma unroll
  for (int it = 0; it < 16; ++it) {
    int r = rb + it * 4;
    tile[r * 65 + c] = src[(size_t)(k0 + r) * 256 + ncol0 + c];
  }
  __syncthreads();
  int kk = threadIdx.x & 63;
#pragma unroll
  for (int it = 0; it < 16; ++it) {
    int nn = rb + it * 4;
    dst[(size_t)(nrow0 + nn) * ldd + kdst0 + kk] = f2bf(tile[kk * 65 + nn]);
  }
}

// ---- GEMM1 (R2-measured best): Y[32768 x 1024] = Xbf @ WbigT^T.
// 256x256 tile, 512 threads (8 waves 2m x 4n -> 128x64/wave), BK=32,
// quad-buffered LDS (4 x 32KB), counted vmcnt + counted lgkmcnt overlap.
template<bool STG, int VM, bool LAST>
__device__ __forceinline__ void g1_tile(int t,
    const unsigned short* __restrict__ gA0, const unsigned short* __restrict__ gB0,
    unsigned short* SH, int w, int abase, int bbase, int sw8,
    bf16x8 (&av)[4], bf16x8 (&bv)[4], bf16x8 (&nav)[4], bf16x8 (&nbv)[4],
    f32x4 (&acc)[8][4]) {
  unsigned short* Ab = SH + ((t & 3) << 14);
  unsigned short* Bb = Ab + 8192;
  bf16x8 av2[4];
  // p1 A-fragments issued early (buffer t already landed)
#pragma unroll
  for (int i = 0; i < 4; ++i)
    av2[i] = *(const bf16x8*)&Ab[(abase + 64 + i * 16) * 32 + sw8];
  __builtin_amdgcn_sched_barrier(0);
  if (STG) {  // stage K-tile t+3 (4 x 1KB per wave)
    unsigned short* dA = SH + (((t + 3) & 3) << 14) + (w << 10);
    const unsigned short* gA = gA0 + (t + 3) * 32;
    ld_lds16(gA, dA);
    ld_lds16(gA + 16 * 1024, dA + 512);
    unsigned short* dB = SH + (((t + 3) & 3) << 14) + 8192 + (w << 10);
    const unsigned short* gB = gB0 + (t + 3) * 32;
    ld_lds16(gB, dB);
    ld_lds16(gB + 16 * 1024, dB + 512);
  }
  // outstanding DS: av/bv (8, oldest) + av2 (4) -> wait p0 frags, keep av2 in flight
  asm volatile("s_waitcnt lgkmcnt(4)");
  __builtin_amdgcn_sched_barrier(0);
  __builtin_amdgcn_s_setprio(1);
#pragma unroll
  for (int i = 0; i < 4; ++i)
#pragma unroll
    for (int j = 0; j < 4; ++j)
      acc[i][j] = __builtin_amdgcn_mfma_f32_16x16x32_bf16(av[i], bv[j], acc[i][j], 0, 0, 0);
  __builtin_amdgcn_s_setprio(0);
  __builtin_amdgcn_sched_barrier(0);
  // buffer t+1 landed guarantee (counted; never 0 mid-loop)
  if constexpr (VM == 8) asm volatile("s_waitcnt vmcnt(8)" ::: "memory");
  else if constexpr (VM == 4) asm volatile("s_waitcnt vmcnt(4)" ::: "memory");
  else if constexpr (VM == 0) asm volatile("s_waitcnt vmcnt(0)" ::: "memory");
  __builtin_amdgcn_s_barrier();
  if constexpr (!LAST) {
    unsigned short* An = SH + (((t + 1) & 3) << 14);
    unsigned short* Bn = An + 8192;
    // next tile p0-A reads: in flight during p1a MFMA
#pragma unroll
    for (int i = 0; i < 4; ++i)
      nav[i] = *(const bf16x8*)&An[(abase + i * 16) * 32 + sw8];
    __builtin_amdgcn_sched_barrier(0);
    // outstanding DS: av2 (4, oldest) + nav (4) -> wait av2, keep nav in flight
    asm volatile("s_waitcnt lgkmcnt(4)");
    __builtin_amdgcn_sched_barrier(0);
    __builtin_amdgcn_s_setprio(1);
#pragma unroll
    for (int i = 0; i < 2; ++i)
#pragma unroll
      for (int j = 0; j < 4; ++j)
        acc[4 + i][j] = __builtin_amdgcn_mfma_f32_16x16x32_bf16(av2[i], bv[j], acc[4 + i][j], 0, 0, 0);
    __builtin_amdgcn_s_setprio(0);
    __builtin_amdgcn_sched_barrier(0);
    // next tile p0-B reads: in flight during p1b MFMA
#pragma unroll
    for (int j = 0; j < 4; ++j)
      nbv[j] = *(const bf16x8*)&Bn[(bbase + j * 16) * 32 + sw8];
    __builtin_amdgcn_sched_barrier(0);
    __builtin_amdgcn_s_setprio(1);
#pragma unroll
    for (int i = 2; i < 4; ++i)
#pragma unroll
      for (int j = 0; j < 4; ++j)
        acc[4 + i][j] = __builtin_amdgcn_mfma_f32_16x16x32_bf16(av2[i], bv[j], acc[4 + i][j], 0, 0, 0);
    __builtin_amdgcn_s_setprio(0);
    // end barrier: all waves' reads of buffer t done before t+1's staging writes it
    __builtin_amdgcn_s_barrier();
  } else {
    asm volatile("s_waitcnt lgkmcnt(0)");
    __builtin_amdgcn_sched_barrier(0);
#pragma unroll
    for (int i = 0; i < 4; ++i)
#pragma unroll
      for (int j = 0; j < 4; ++j)
        acc[4 + i][j] = __builtin_amdgcn_mfma_f32_16x16x32_bf16(av2[i], bv[j], acc[4 + i][j], 0, 0, 0);
  }
}

__global__ __launch_bounds__(512, 2)
void diagcn_gemm1(const unsigned short* __restrict__ A, const unsigned short* __restrict__ BT,
                  unsigned short* __restrict__ Y) {
  __shared__ unsigned short SH[65536];   // 128 KB: 4 bufs x (A 16KB + B 16KB)
  const int tid = threadIdx.x;
  const int w = tid >> 6, lane = tid & 63;
  const int quad = lane >> 4, l15 = lane & 15;
  const int wm = w >> 2, wn = w & 3;
  const int b = blockIdx.x;
  // XCD-aware bijective swizzle: 512 blocks = 8 XCDs x 64; n fastest within XCD
  const int wg = ((b & 7) << 6) + (b >> 3);
  const int m0 = (wg >> 2) << 8;
  const int n0 = (wg & 3) << 8;
  const int abase = wm * 128 + l15;                       // wave A-row base
  const int bbase = wn * 64 + l15;                        // wave B-row base
  const int sw8 = ((quad ^ ((l15 >> 1) & 3)) << 3);       // read-side swizzle (thread-const)
  const int csrc8 = (((lane & 3) ^ ((lane >> 3) & 3)) << 3); // source-side inverse swizzle
  const unsigned short* gA0 = A + (size_t)(m0 + w * 32 + (lane >> 2)) * 1024 + csrc8;
  const unsigned short* gB0 = BT + (size_t)(n0 + w * 32 + (lane >> 2)) * 1024 + csrc8;

  f32x4 acc[8][4] = {};
  bf16x8 avA[4], bvA[4], avB[4], bvB[4];

  // prologue: stage K-tiles 0,1,2 (12 loads/wave in flight)
#pragma unroll
  for (int tt = 0; tt < 3; ++tt) {
    unsigned short* dA = SH + (tt << 14) + (w << 10);
    ld_lds16(gA0 + tt * 32, dA);
    ld_lds16(gA0 + tt * 32 + 16 * 1024, dA + 512);
    unsigned short* dB = SH + (tt << 14) + 8192 + (w << 10);
    ld_lds16(gB0 + tt * 32, dB);
    ld_lds16(gB0 + tt * 32 + 16 * 1024, dB + 512);
  }
  asm volatile("s_waitcnt vmcnt(8)" ::: "memory");   // tile 0 landed (oldest 4 of 12)
  __builtin_amdgcn_s_barrier();
  // pre-issue tile 0 p0 fragments (stay outstanding into the loop)
#pragma unroll
  for (int i = 0; i < 4; ++i)
    avA[i] = *(const bf16x8*)&SH[(abase + i * 16) * 32 + sw8];
#pragma unroll
  for (int j = 0; j < 4; ++j)
    bvA[j] = *(const bf16x8*)&SH[8192 + (bbase + j * 16) * 32 + sw8];
  __builtin_amdgcn_sched_barrier(0);

#pragma unroll 1
  for (int tt = 0; tt < 14; ++tt) {   // tiles 0..27, role-swapped pairs
    g1_tile<true, 8, false>(2 * tt, gA0, gB0, SH, w, abase, bbase, sw8,
                            avA, bvA, avB, bvB, acc);
    g1_tile<true, 8, false>(2 * tt + 1, gA0, gB0, SH, w, abase, bbase, sw8,
                            avB, bvB, avA, bvA, acc);
  }
  g1_tile<true, 8, false>(28, gA0, gB0, SH, w, abase, bbase, sw8, avA, bvA, avB, bvB, acc);
  g1_tile<false, 4, false>(29, gA0, gB0, SH, w, abase, bbase, sw8, avB, bvB, avA, bvA, acc);
  g1_tile<false, 0, false>(30, gA0, gB0, SH, w, abase, bbase, sw8, avA, bvA, avB, bvB, acc);
  g1_tile<false, -1, true>(31, gA0, gB0, SH, w, abase, bbase, sw8, avB, bvB, avA, bvA, acc);

  // epilogue: C/D mapping col=lane&15, row=quad*4+r
#pragma unroll
  for (int i = 0; i < 8; ++i)
#pragma unroll
    for (int j = 0; j < 4; ++j) {
      const int row = m0 + wm * 128 + i * 16 + quad * 4;
      const int col = n0 + wn * 64 + j * 16 + l15;
#pragma unroll
      for (int r = 0; r < 4; ++r)
        Y[(size_t)(row + r) * 1024 + col] = f2bf(acc[i][j][r]);
    }
}

// ---- RGCN aggregate, 2 nodes per wave (8 ch/lane, 16B loads), branchless window.
// h_i = Yroot_i + b + sum_r mean_{j in win, rel=r} Y_r[j]; bf16 h -> A2[:,0:256].
__global__ __launch_bounds__(256)
void diagcn_h(const unsigned short* __restrict__ Y, const int* __restrict__ spk,
              const float* __restrict__ brgcn, unsigned short* __restrict__ A2) {
  int b = blockIdx.x;
  int wv = threadIdx.x >> 6, lane = threadIdx.x & 63;
  int half = lane >> 5, li = lane & 31, c0 = li << 3;
  int node = ((b & 7) << 12) + ((b >> 3) << 3) + wv * 2 + half;
  int p = node & 255, dbase = node - p;
  int si = spk[node];
  float a0[8] = {}, a1[8] = {};
  float n0 = 0.f, n1 = 0.f;
#pragma unroll
  for (int d = -4; d <= 4; ++d) {
    int pj = p + d;
    float w = (pj >= 0 && pj < 256) ? 1.f : 0.f;
    int jc = pj < 0 ? 0 : (pj > 255 ? 255 : pj);
    int nj = dbase + jc;
    int rel = si & spk[nj];
    u16x8 v = *(const u16x8*)&Y[(size_t)nj * 1024 + (rel << 8) + c0];
    float w1 = rel ? w : 0.f, w0 = rel ? 0.f : w;
#pragma unroll
    for (int k = 0; k < 8; ++k) {
      float f = bf2f(v[k]);
      a0[k] += f * w0; a1[k] += f * w1;
    }
    n0 += w0; n1 += w1;
  }
  u16x8 vr = *(const u16x8*)&Y[(size_t)node * 1024 + 512 + c0];
  float i0 = 1.f / fmaxf(n0, 1.f), i1 = 1.f / fmaxf(n1, 1.f);
  u16x8 u;
#pragma unroll
  for (int k = 0; k < 8; ++k)
    u[k] = f2bf(bf2f(vr[k]) + brgcn[c0 + k] + a0[k] * i0 + a1[k] * i1);
  *(u16x8*)&A2[(size_t)node * 512 + c0] = u;
}

// ---- GraphConv neighbor sum (aggr=add over window incl. self), 2 nodes/wave.
__global__ __launch_bounds__(256)
void diagcn_neigh(unsigned short* __restrict__ A2) {
  int b = blockIdx.x;
  int wv = threadIdx.x >> 6, lane = threadIdx.x & 63;
  int half = lane >> 5, li = lane & 31, c0 = li << 3;
  int node = ((b & 7) << 12) + ((b >> 3) << 3) + wv * 2 + half;
  int p = node & 255, dbase = node - p;
  float s[8] = {};
#pragma unroll
  for (int d = -4; d <= 4; ++d) {
    int pj = p + d;
    float w = (pj >= 0 && pj < 256) ? 1.f : 0.f;
    int jc = pj < 0 ? 0 : (pj > 255 ? 255 : pj);
    u16x8 v = *(const u16x8*)&A2[(size_t)(dbase + jc) * 512 + c0];
#pragma unroll
    for (int k = 0; k < 8; ++k) s[k] += bf2f(v[k]) * w;
  }
  u16x8 u;
#pragma unroll
  for (int k = 0; k < 8; ++k) u[k] = f2bf(s[k]);
  *(u16x8*)&A2[(size_t)node * 512 + 256 + c0] = u;
}

// ---- GEMM2 v2 + fused epilogue. 64x256 tile (full H per block), K=512.
// ZERO-LDS K-loop: A2 (32MB, HBM/L3 stream) and WsmT (256KB, L2-resident) are
// loaded per-lane directly as MFMA fragments — operand values and accumulation
// order identical to the old LDS-staged path (row ra = w*16+l15, k-chunk
// kb = ks*4+quad), so numerics are unchanged. No barriers / no inter-wave
// coupling in the K-loop: waves free-run and the compiler pipelines loads,
// fixing the 87 us latency-bound profile (MfmaUtil 3.6%, HBM 313 GB/s, all
// pipes idle) caused by per-tile vmcnt(0)+syncthreads drains at 2 blocks/CU.
// Wave access pattern: 16 rows x 4 quads = 64 contiguous bytes per row.
__global__ __launch_bounds__(256)
void diagcn_gemm2(const unsigned short* __restrict__ A, const unsigned short* __restrict__ BT,
                  const unsigned short* __restrict__ Y, const float* __restrict__ Wcls,
                  const float* __restrict__ bcls, const float* __restrict__ brel,
                  const float* __restrict__ bskip, const int* __restrict__ labels,
                  float* __restrict__ out, float* __restrict__ loss) {
  const int K = 512;
  __shared__ float Wc[2312];   // [0,1792) Wcls | [1792,1799) bcls | [1800,2056) brel | [2056,2312) bskip
  for (int i = threadIdx.x; i < 2312; i += 256) {
    float v;
    if (i < 1792) v = Wcls[i];
    else if (i < 1799) v = bcls[i - 1792];
    else if (i < 1800) v = 0.f;
    else if (i < 2056) v = brel[i - 1800];
    else v = bskip[i - 2056];
    Wc[i] = v;
  }
  __syncthreads();
  const int tid = threadIdx.x;
  const int w = tid >> 6, lane = tid & 63;
  const int quad = lane >> 4, l15 = lane & 15;
  const int b = blockIdx.x;
  const int m0 = (((b & 7) << 6) + (b >> 3)) << 6;   // 512 m-tiles of 64 rows

  f32x4 acc[16] = {};
  // per-lane fragment bases: row (m0 + w*16 + l15), k-chunk quad*8 within each ks-half
  const unsigned short* Ab = A + (size_t)(m0 + w * 16 + l15) * K + quad * 8;
  const unsigned short* Bb = BT + (size_t)l15 * K + quad * 8;

#pragma unroll 2
  for (int k0 = 0; k0 < K; k0 += 64) {
#pragma unroll
    for (int ks = 0; ks < 2; ++ks) {
      bf16x8 av = *(const bf16x8*)(Ab + k0 + ks * 32);
#pragma unroll
      for (int j = 0; j < 16; ++j) {
        bf16x8 bv = *(const bf16x8*)(Bb + (size_t)j * 16 * K + k0 + ks * 32);
        acc[j] = __builtin_amdgcn_mfma_f32_16x16x32_bf16(av, bv, acc[j], 0, 0, 0);
      }
    }
  }

  // ---- epilogue: bias + skip, classifier partials (unchanged)
  float wsum[4][7] = {};
#pragma unroll
  for (int j = 0; j < 16; ++j) {
    int col = j * 16 + l15;
    float bb = Wc[1800 + col] + Wc[2056 + col];
#pragma unroll
    for (int r = 0; r < 4; ++r) {
      int row = m0 + w * 16 + quad * 4 + r;
      float z = acc[j][r] + bb + bf2f(Y[(size_t)row * 1024 + 768 + col]);
#pragma unroll
      for (int c = 0; c < 7; ++c) wsum[r][c] += z * Wc[col * 7 + c];
    }
  }
  // reduce over the 16 lanes of each quad (cols) -> every lane holds full row dots
#pragma unroll
  for (int o = 1; o < 16; o <<= 1)
#pragma unroll
    for (int r = 0; r < 4; ++r)
#pragma unroll
      for (int c = 0; c < 7; ++c) wsum[r][c] += __shfl_xor(wsum[r][c], o, 64);

  float lsum = 0.f;
#pragma unroll
  for (int r = 0; r < 4; ++r) {
    int row = m0 + w * 16 + quad * 4 + r;
    float o7[7], mx = -1e30f;
#pragma unroll
    for (int c = 0; c < 7; ++c) {
      o7[c] = wsum[r][c] + Wc[1792 + c];
      mx = fmaxf(mx, o7[c]);
    }
    if (l15 < 7) out[(size_t)row * 7 + l15] = o7[l15];
    float s = 0.f;
#pragma unroll
    for (int c = 0; c < 7; ++c) s += expf(o7[c] - mx);
    int lab = labels[row];
    lsum += mx + logf(s) - o7[lab];
  }
  // quad-totals are lane-identical; combine the 4 quads
  lsum += __shfl_xor(lsum, 16, 64);
  lsum += __shfl_xor(lsum, 32, 64);
  if (lane == 0) atomicAdd(loss, lsum * (1.0f / (float)NN));
}

extern "C" void kernel_launch(void* const* d_in, const int* in_sizes, int n_in,
                              void* d_out, int out_size, void* d_ws, size_t ws_size,
                              hipStream_t stream) {
  const float* x      = (const float*)d_in[0];
  const int* speakers = (const int*)d_in[2];
  const int* labels   = (const int*)d_in[3];
  const float* Wrgcn  = (const float*)d_in[6];
  const float* Wroot  = (const float*)d_in[7];
  const float* brgcn  = (const float*)d_in[8];
  const float* Wrel   = (const float*)d_in[9];
  const float* brel   = (const float*)d_in[10];
  const float* Wgrt   = (const float*)d_in[11];
  const float* Wskip  = (const float*)d_in[12];
  const float* bskip  = (const float*)d_in[13];
  const float* Wcls   = (const float*)d_in[14];
  const float* bcls   = (const float*)d_in[15];
  float* out = (float*)d_out;
  float* loss = out + (size_t)NN * 7;

  // workspace layout (bytes)
  const size_t OFF_XBF  = 0;                  // 67,108,864  (bf16 X)
  const size_t OFF_WBIG = 67108864;           //  2,097,152
  const size_t OFF_WSM  = 69206016;           //    262,144
  const size_t OFF_Y    = 69468160;           // 67,108,864  (bf16 [Y0|Y1|Yroot|Yskip])
  const size_t OFF_A2   = 136577024;          // 33,554,432  (bf16 [h|neigh])
  const size_t NEED     = 170131456;
  if (ws_size < NEED) return;

  char* ws = (char*)d_ws;
  unsigned short* Xbf   = (unsigned short*)(ws + OFF_XBF);
  unsigned short* WbigT = (unsigned short*)(ws + OFF_WBIG);
  unsigned short* WsmT  = (unsigned short*)(ws + OFF_WSM);
  unsigned short* Y     = (unsigned short*)(ws + OFF_Y);
  unsigned short* A2    = (unsigned short*)(ws + OFF_A2);

  diagcn_prep<<<dim3(16672), dim3(256), 0, stream>>>(x, Wrgcn, Wroot, Wskip, Wgrt, Wrel,
                                                     Xbf, WbigT, WsmT, loss);
  diagcn_gemm1<<<dim3(512), dim3(512), 0, stream>>>(Xbf, WbigT, Y);
  diagcn_h<<<dim3(NN / 8), dim3(256), 0, stream>>>(Y, speakers, brgcn, A2);
  diagcn_neigh<<<dim3(NN / 8), dim3(256), 0, stream>>>(A2);
  diagcn_gemm2<<<dim3(512), dim3(256), 0, stream>>>(A2, WsmT, Y, Wcls, bcls, brel, bskip,
                                                    labels, out, loss);
}

// Round 10
// 371.049 us; speedup vs baseline: 1.1063x; 1.1063x over previous
//
#include <hip/hip_runtime.h>

// Problem constants (fixed by reference): B=128, L=256, F=P=4, IN=1024, H=256, C=7
#define NN 32768        // N = B*L
#define INF 1024
#define HF 256

typedef __bf16 bf16x8 __attribute__((ext_vector_type(8)));
typedef float f32x4 __attribute__((ext_vector_type(4)));
typedef unsigned short u16x8 __attribute__((ext_vector_type(8)));

__device__ __forceinline__ float bf2f(unsigned short u) {
  union { unsigned int i; float f; } v; v.i = ((unsigned int)u) << 16; return v.f;
}
__device__ __forceinline__ unsigned short f2bf(float f) {
  union { float f; unsigned int i; } v; v.f = f;
  unsigned int x = v.i;
  return (unsigned short)((x + 0x7fffu + ((x >> 16) & 1u)) >> 16);  // RNE
}

// async global->LDS, 16B per lane; dest = lds base (wave-uniform) + lane*16
__device__ __forceinline__ void ld_lds16(const unsigned short* g, unsigned short* l) {
  __builtin_amdgcn_global_load_lds(
      (__attribute__((address_space(1))) const unsigned int*)g,
      (__attribute__((address_space(3))) unsigned int*)l, 16, 0, 0);
}

// ---- prep:
//  blocks [0,16384):        x fp32 -> bf16, one-shot, 32B read / 16B write per thread
//  blocks [16384,16384+288): weight repack via 64x64 LDS transpose
// WbigT[n][k] (1024x1024) = [W0|W1|Wroot|Wskip]^T ; WsmT[n][k] (256x512) = [Wgrt;Wrel]^T
__global__ __launch_bounds__(256)
void diagcn_prep(const float* __restrict__ x, const float* __restrict__ Wrgcn,
                 const float* __restrict__ Wroot, const float* __restrict__ Wskip,
                 const float* __restrict__ Wgrt, const float* __restrict__ Wrel,
                 unsigned short* __restrict__ Xbf, unsigned short* __restrict__ WbigT,
                 unsigned short* __restrict__ WsmT, float* __restrict__ loss) {
  int bid = blockIdx.x;
  if (bid < 16384) {
    if (bid == 0 && threadIdx.x == 0) loss[0] = 0.f;
    int gid = bid * 256 + threadIdx.x;          // 4,194,304 threads, 8 floats each
    const float4* xv = (const float4*)x;
    float4 a = xv[2 * gid], b2 = xv[2 * gid + 1];
    u16x8 o;
    o[0] = f2bf(a.x); o[1] = f2bf(a.y); o[2] = f2bf(a.z); o[3] = f2bf(a.w);
    o[4] = f2bf(b2.x); o[5] = f2bf(b2.y); o[6] = f2bf(b2.z); o[7] = f2bf(b2.w);
    *(u16x8*)&Xbf[(size_t)gid * 8] = o;
    return;
  }
  __shared__ float tile[64 * 65];
  int tb = bid - 16384;
  const float* src;
  int k0, ncol0;
  unsigned short* dst;
  int ldd, nrow0;
  if (tb < 256) {            // WbigT tiles: tn 0..15, tk 0..15
    int tn = tb >> 4, tk = tb & 15;
    int mat = tn >> 2;
    src = (mat == 0) ? Wrgcn : (mat == 1) ? (Wrgcn + 262144) : (mat == 2) ? Wroot : Wskip;
    k0 = tk * 64; ncol0 = (tn & 3) * 64;
    dst = WbigT; ldd = 1024; nrow0 = tn * 64;
  } else {                   // WsmT tiles: tn 0..3, tk 0..7
    int t2 = tb - 256;
    int tn = t2 >> 3, tk = t2 & 7;
    src = (tk < 4) ? Wgrt : Wrel;
    k0 = (tk & 3) * 64; ncol0 = tn * 64;
    dst = WsmT; ldd = 512; nrow0 = tn * 64;
  }
  int kdst0 = (tb < 256) ? k0 : (((tb - 256) & 7) * 64);
  int c = threadIdx.x & 63, rb = threadIdx.x >> 6;
#pragma unroll
  for (int it = 0; it < 16; ++it) {
    int r = rb + it * 4;
    tile[r * 65 + c] = src[(size_t)(k0 + r) * 256 + ncol0 + c];
  }
  __syncthreads();
  int kk = threadIdx.x & 63;
#pragma unroll
  for (int it = 0; it < 16; ++it) {
    int nn = rb + it * 4;
    dst[(size_t)(nrow0 + nn) * ldd + kdst0 + kk] = f2bf(tile[kk * 65 + nn]);
  }
}

// ---- GEMM1 (R2-measured best): Y[32768 x 1024] = Xbf @ WbigT^T.
// 256x256 tile, 512 threads (8 waves 2m x 4n -> 128x64/wave), BK=32,
// quad-buffered LDS (4 x 32KB), counted vmcnt + counted lgkmcnt overlap.
template<bool STG, int VM, bool LAST>
__device__ __forceinline__ void g1_tile(int t,
    const unsigned short* __restrict__ gA0, const unsigned short* __restrict__ gB0,
    unsigned short* SH, int w, int abase, int bbase, int sw8,
    bf16x8 (&av)[4], bf16x8 (&bv)[4], bf16x8 (&nav)[4], bf16x8 (&nbv)[4],
    f32x4 (&acc)[8][4]) {
  unsigned short* Ab = SH + ((t & 3) << 14);
  unsigned short* Bb = Ab + 8192;
  bf16x8 av2[4];
  // p1 A-fragments issued early (buffer t already landed)
#pragma unroll
  for (int i = 0; i < 4; ++i)
    av2[i] = *(const bf16x8*)&Ab[(abase + 64 + i * 16) * 32 + sw8];
  __builtin_amdgcn_sched_barrier(0);
  if (STG) {  // stage K-tile t+3 (4 x 1KB per wave)
    unsigned short* dA = SH + (((t + 3) & 3) << 14) + (w << 10);
    const unsigned short* gA = gA0 + (t + 3) * 32;
    ld_lds16(gA, dA);
    ld_lds16(gA + 16 * 1024, dA + 512);
    unsigned short* dB = SH + (((t + 3) & 3) << 14) + 8192 + (w << 10);
    const unsigned short* gB = gB0 + (t + 3) * 32;
    ld_lds16(gB, dB);
    ld_lds16(gB + 16 * 1024, dB + 512);
  }
  // outstanding DS: av/bv (8, oldest) + av2 (4) -> wait p0 frags, keep av2 in flight
  asm volatile("s_waitcnt lgkmcnt(4)");
  __builtin_amdgcn_sched_barrier(0);
  __builtin_amdgcn_s_setprio(1);
#pragma unroll
  for (int i = 0; i < 4; ++i)
#pragma unroll
    for (int j = 0; j < 4; ++j)
      acc[i][j] = __builtin_amdgcn_mfma_f32_16x16x32_bf16(av[i], bv[j], acc[i][j], 0, 0, 0);
  __builtin_amdgcn_s_setprio(0);
  __builtin_amdgcn_sched_barrier(0);
  // buffer t+1 landed guarantee (counted; never 0 mid-loop)
  if constexpr (VM == 8) asm volatile("s_waitcnt vmcnt(8)" ::: "memory");
  else if constexpr (VM == 4) asm volatile("s_waitcnt vmcnt(4)" ::: "memory");
  else if constexpr (VM == 0) asm volatile("s_waitcnt vmcnt(0)" ::: "memory");
  __builtin_amdgcn_s_barrier();
  if constexpr (!LAST) {
    unsigned short* An = SH + (((t + 1) & 3) << 14);
    unsigned short* Bn = An + 8192;
    // next tile p0-A reads: in flight during p1a MFMA
#pragma unroll
    for (int i = 0; i < 4; ++i)
      nav[i] = *(const bf16x8*)&An[(abase + i * 16) * 32 + sw8];
    __builtin_amdgcn_sched_barrier(0);
    // outstanding DS: av2 (4, oldest) + nav (4) -> wait av2, keep nav in flight
    asm volatile("s_waitcnt lgkmcnt(4)");
    __builtin_amdgcn_sched_barrier(0);
    __builtin_amdgcn_s_setprio(1);
#pragma unroll
    for (int i = 0; i < 2; ++i)
#pragma unroll
      for (int j = 0; j < 4; ++j)
        acc[4 + i][j] = __builtin_amdgcn_mfma_f32_16x16x32_bf16(av2[i], bv[j], acc[4 + i][j], 0, 0, 0);
    __builtin_amdgcn_s_setprio(0);
    __builtin_amdgcn_sched_barrier(0);
    // next tile p0-B reads: in flight during p1b MFMA
#pragma unroll
    for (int j = 0; j < 4; ++j)
      nbv[j] = *(const bf16x8*)&Bn[(bbase + j * 16) * 32 + sw8];
    __builtin_amdgcn_sched_barrier(0);
    __builtin_amdgcn_s_setprio(1);
#pragma unroll
    for (int i = 2; i < 4; ++i)
#pragma unroll
      for (int j = 0; j < 4; ++j)
        acc[4 + i][j] = __builtin_amdgcn_mfma_f32_16x16x32_bf16(av2[i], bv[j], acc[4 + i][j], 0, 0, 0);
    __builtin_amdgcn_s_setprio(0);
    // end barrier: all waves' reads of buffer t done before t+1's staging writes it
    __builtin_amdgcn_s_barrier();
  } else {
    asm volatile("s_waitcnt lgkmcnt(0)");
    __builtin_amdgcn_sched_barrier(0);
#pragma unroll
    for (int i = 0; i < 4; ++i)
#pragma unroll
      for (int j = 0; j < 4; ++j)
        acc[4 + i][j] = __builtin_amdgcn_mfma_f32_16x16x32_bf16(av2[i], bv[j], acc[4 + i][j], 0, 0, 0);
  }
}

__global__ __launch_bounds__(512, 2)
void diagcn_gemm1(const unsigned short* __restrict__ A, const unsigned short* __restrict__ BT,
                  unsigned short* __restrict__ Y) {
  __shared__ unsigned short SH[65536];   // 128 KB: 4 bufs x (A 16KB + B 16KB)
  const int tid = threadIdx.x;
  const int w = tid >> 6, lane = tid & 63;
  const int quad = lane >> 4, l15 = lane & 15;
  const int wm = w >> 2, wn = w & 3;
  const int b = blockIdx.x;
  // XCD-aware bijective swizzle: 512 blocks = 8 XCDs x 64; n fastest within XCD
  const int wg = ((b & 7) << 6) + (b >> 3);
  const int m0 = (wg >> 2) << 8;
  const int n0 = (wg & 3) << 8;
  const int abase = wm * 128 + l15;                       // wave A-row base
  const int bbase = wn * 64 + l15;                        // wave B-row base
  const int sw8 = ((quad ^ ((l15 >> 1) & 3)) << 3);       // read-side swizzle (thread-const)
  const int csrc8 = (((lane & 3) ^ ((lane >> 3) & 3)) << 3); // source-side inverse swizzle
  const unsigned short* gA0 = A + (size_t)(m0 + w * 32 + (lane >> 2)) * 1024 + csrc8;
  const unsigned short* gB0 = BT + (size_t)(n0 + w * 32 + (lane >> 2)) * 1024 + csrc8;

  f32x4 acc[8][4] = {};
  bf16x8 avA[4], bvA[4], avB[4], bvB[4];

  // prologue: stage K-tiles 0,1,2 (12 loads/wave in flight)
#pragma unroll
  for (int tt = 0; tt < 3; ++tt) {
    unsigned short* dA = SH + (tt << 14) + (w << 10);
    ld_lds16(gA0 + tt * 32, dA);
    ld_lds16(gA0 + tt * 32 + 16 * 1024, dA + 512);
    unsigned short* dB = SH + (tt << 14) + 8192 + (w << 10);
    ld_lds16(gB0 + tt * 32, dB);
    ld_lds16(gB0 + tt * 32 + 16 * 1024, dB + 512);
  }
  asm volatile("s_waitcnt vmcnt(8)" ::: "memory");   // tile 0 landed (oldest 4 of 12)
  __builtin_amdgcn_s_barrier();
  // pre-issue tile 0 p0 fragments (stay outstanding into the loop)
#pragma unroll
  for (int i = 0; i < 4; ++i)
    avA[i] = *(const bf16x8*)&SH[(abase + i * 16) * 32 + sw8];
#pragma unroll
  for (int j = 0; j < 4; ++j)
    bvA[j] = *(const bf16x8*)&SH[8192 + (bbase + j * 16) * 32 + sw8];
  __builtin_amdgcn_sched_barrier(0);

#pragma unroll 1
  for (int tt = 0; tt < 14; ++tt) {   // tiles 0..27, role-swapped pairs
    g1_tile<true, 8, false>(2 * tt, gA0, gB0, SH, w, abase, bbase, sw8,
                            avA, bvA, avB, bvB, acc);
    g1_tile<true, 8, false>(2 * tt + 1, gA0, gB0, SH, w, abase, bbase, sw8,
                            avB, bvB, avA, bvA, acc);
  }
  g1_tile<true, 8, false>(28, gA0, gB0, SH, w, abase, bbase, sw8, avA, bvA, avB, bvB, acc);
  g1_tile<false, 4, false>(29, gA0, gB0, SH, w, abase, bbase, sw8, avB, bvB, avA, bvA, acc);
  g1_tile<false, 0, false>(30, gA0, gB0, SH, w, abase, bbase, sw8, avA, bvA, avB, bvB, acc);
  g1_tile<false, -1, true>(31, gA0, gB0, SH, w, abase, bbase, sw8, avB, bvB, avA, bvA, acc);

  // epilogue: C/D mapping col=lane&15, row=quad*4+r
#pragma unroll
  for (int i = 0; i < 8; ++i)
#pragma unroll
    for (int j = 0; j < 4; ++j) {
      const int row = m0 + wm * 128 + i * 16 + quad * 4;
      const int col = n0 + wn * 64 + j * 16 + l15;
#pragma unroll
      for (int r = 0; r < 4; ++r)
        Y[(size_t)(row + r) * 1024 + col] = f2bf(acc[i][j][r]);
    }
}

// ---- RGCN aggregate, 2 nodes per wave (8 ch/lane, 16B loads), branchless window.
// h_i = Yroot_i + b + sum_r mean_{j in win, rel=r} Y_r[j]; bf16 h -> A2[:,0:256].
__global__ __launch_bounds__(256)
void diagcn_h(const unsigned short* __restrict__ Y, const int* __restrict__ spk,
              const float* __restrict__ brgcn, unsigned short* __restrict__ A2) {
  int b = blockIdx.x;
  int wv = threadIdx.x >> 6, lane = threadIdx.x & 63;
  int half = lane >> 5, li = lane & 31, c0 = li << 3;
  int node = ((b & 7) << 12) + ((b >> 3) << 3) + wv * 2 + half;
  int p = node & 255, dbase = node - p;
  int si = spk[node];
  float a0[8] = {}, a1[8] = {};
  float n0 = 0.f, n1 = 0.f;
#pragma unroll
  for (int d = -4; d <= 4; ++d) {
    int pj = p + d;
    float w = (pj >= 0 && pj < 256) ? 1.f : 0.f;
    int jc = pj < 0 ? 0 : (pj > 255 ? 255 : pj);
    int nj = dbase + jc;
    int rel = si & spk[nj];
    u16x8 v = *(const u16x8*)&Y[(size_t)nj * 1024 + (rel << 8) + c0];
    float w1 = rel ? w : 0.f, w0 = rel ? 0.f : w;
#pragma unroll
    for (int k = 0; k < 8; ++k) {
      float f = bf2f(v[k]);
      a0[k] += f * w0; a1[k] += f * w1;
    }
    n0 += w0; n1 += w1;
  }
  u16x8 vr = *(const u16x8*)&Y[(size_t)node * 1024 + 512 + c0];
  float i0 = 1.f / fmaxf(n0, 1.f), i1 = 1.f / fmaxf(n1, 1.f);
  u16x8 u;
#pragma unroll
  for (int k = 0; k < 8; ++k)
    u[k] = f2bf(bf2f(vr[k]) + brgcn[c0 + k] + a0[k] * i0 + a1[k] * i1);
  *(u16x8*)&A2[(size_t)node * 512 + c0] = u;
}

// ---- GraphConv neighbor sum (aggr=add over window incl. self), 2 nodes/wave.
__global__ __launch_bounds__(256)
void diagcn_neigh(unsigned short* __restrict__ A2) {
  int b = blockIdx.x;
  int wv = threadIdx.x >> 6, lane = threadIdx.x & 63;
  int half = lane >> 5, li = lane & 31, c0 = li << 3;
  int node = ((b & 7) << 12) + ((b >> 3) << 3) + wv * 2 + half;
  int p = node & 255, dbase = node - p;
  float s[8] = {};
#pragma unroll
  for (int d = -4; d <= 4; ++d) {
    int pj = p + d;
    float w = (pj >= 0 && pj < 256) ? 1.f : 0.f;
    int jc = pj < 0 ? 0 : (pj > 255 ? 255 : pj);
    u16x8 v = *(const u16x8*)&A2[(size_t)(dbase + jc) * 512 + c0];
#pragma unroll
    for (int k = 0; k < 8; ++k) s[k] += bf2f(v[k]) * w;
  }
  u16x8 u;
#pragma unroll
  for (int k = 0; k < 8; ++k) u[k] = f2bf(s[k]);
  *(u16x8*)&A2[(size_t)node * 512 + 256 + c0] = u;
}

// ---- GEMM2 v3 + fused epilogue. 64x256 tile, K=512, BK=64 (8 K-tiles).
// Same staging/fragment address math as the verified R8 kernel, but the per-tile
// {vmcnt(0)+syncthreads} drain (measured: 87us, MfmaUtil 3.6%, all pipes idle =
// latency-serialized) is replaced by gemm1's counted double-buffer pipeline:
// 2 x 40KB buffers, prefetch depth 2, per-tile gate vmcnt(10) (= tile t+1's 10
// loads/thread retired; t+2 in flight), vmcnt(0) only at the tail. Wc biases ->
// direct global reads (L2-hot) so LDS stays 80KB = 2 blocks/CU. The Y-skip tile
// (32KB) is staged coalesced into freed buf0 during tile 7's MFMA, replacing the
// 64 scalar 2B Y-reads per thread.
__global__ __launch_bounds__(256)
void diagcn_gemm2(const unsigned short* __restrict__ A, const unsigned short* __restrict__ BT,
                  const unsigned short* __restrict__ Y, const float* __restrict__ Wcls,
                  const float* __restrict__ bcls, const float* __restrict__ brel,
                  const float* __restrict__ bskip, const int* __restrict__ labels,
                  float* __restrict__ out, float* __restrict__ loss) {
  const int K = 512;
  __shared__ unsigned short SH[40960];   // 80 KB: 2 bufs x (A 4096 + B 16384 elems)
  const int tid = threadIdx.x;
  const int w = tid >> 6, lane = tid & 63;
  const int quad = lane >> 4, l15 = lane & 15;
  const int b = blockIdx.x;
  const int m0 = (((b & 7) << 6) + (b >> 3)) << 6;   // 512 m-tiles of 64 rows
  const int rowg = lane >> 3;
  const int kbsw = (lane & 7) ^ rowg;

  f32x4 acc[16] = {};
  const unsigned short* Abase = A + (size_t)m0 * K + kbsw * 8;
  const unsigned short* Bbase = BT + kbsw * 8;
  // per-lane Y source: rows m0 + g*2 + (lane>>5), cols 768 + (lane&31)*8
  const unsigned short* Ybase = Y + (size_t)(m0 + (lane >> 5)) * 1024 + 768 + (lane & 31) * 8;

  // ---- stage tile t (k0 = t*64) into buffer buf: 2 A-calls + 8 B-calls per wave
#define G2_STAGE(t, buf)                                                        \
  {                                                                             \
    unsigned short* As_ = SH + (buf) * 20480;                                   \
    unsigned short* Bs_ = As_ + 4096;                                           \
    int k0_ = (t) * 64;                                                         \
    _Pragma("unroll")                                                           \
    for (int i = 0; i < 2; ++i) {                                               \
      int grp = w * 2 + i;                                                      \
      ld_lds16(Abase + (size_t)(grp * 8 + rowg) * K + k0_, &As_[grp * 512]);    \
    }                                                                           \
    _Pragma("unroll")                                                           \
    for (int i = 0; i < 8; ++i) {                                               \
      int grp = w * 8 + i;                                                      \
      ld_lds16(Bbase + (size_t)(grp * 8 + rowg) * K + k0_, &Bs_[grp * 512]);    \
    }                                                                           \
  }
  // ---- consume tile in buffer buf (R8 fragment math, compiler-scheduled)
#define G2_COMPUTE(buf)                                                         \
  {                                                                             \
    const unsigned short* As_ = SH + (buf) * 20480;                             \
    const unsigned short* Bs_ = As_ + 4096;                                     \
    _Pragma("unroll")                                                           \
    for (int ks = 0; ks < 2; ++ks) {                                            \
      int kb = ks * 4 + quad;                                                   \
      int ra = w * 16 + l15;                                                    \
      bf16x8 av = *(const bf16x8*)&As_[ra * 64 + ((kb ^ (ra & 7)) << 3)];       \
      _Pragma("unroll")                                                         \
      for (int j = 0; j < 16; ++j) {                                            \
        int rb2 = j * 16 + l15;                                                 \
        bf16x8 bv = *(const bf16x8*)&Bs_[rb2 * 64 + ((kb ^ (rb2 & 7)) << 3)];   \
        acc[j] = __builtin_amdgcn_mfma_f32_16x16x32_bf16(av, bv, acc[j], 0, 0, 0); \
      }                                                                         \
    }                                                                           \
  }

  // prologue: tiles 0,1 staged (20 loads/thread in flight)
  G2_STAGE(0, 0);
  G2_STAGE(1, 1);
  asm volatile("s_waitcnt vmcnt(10)" ::: "memory");   // tile 0 landed
  __builtin_amdgcn_s_barrier();

#pragma unroll 1
  for (int t = 0; t < 6; ++t) {
    G2_COMPUTE(t & 1);
    asm volatile("s_waitcnt lgkmcnt(0)" ::: "memory"); // frag reads returned (fence)
    __builtin_amdgcn_s_barrier();                      // all waves done with this buf
    G2_STAGE(t + 2, t & 1);                            // overwrite just-consumed buf
    asm volatile("s_waitcnt vmcnt(10)" ::: "memory");  // tile t+1 landed; t+2 in flight
    __builtin_amdgcn_s_barrier();
  }
  G2_COMPUTE(0);                                       // tile 6
  asm volatile("s_waitcnt lgkmcnt(0)" ::: "memory");
  __builtin_amdgcn_s_barrier();
  asm volatile("s_waitcnt vmcnt(0)" ::: "memory");     // tile 7 landed
  __builtin_amdgcn_s_barrier();
  // stage Y-skip tile into freed buf0 (latency hides under tile 7's MFMA)
#pragma unroll
  for (int i = 0; i < 8; ++i) {
    int g = w * 8 + i;
    ld_lds16(Ybase + (size_t)g * 2048, &SH[g * 512]);  // SH[row_local*256 + col]
  }
  G2_COMPUTE(1);                                       // tile 7
  asm volatile("s_waitcnt vmcnt(0)" ::: "memory");     // Y landed
  __builtin_amdgcn_s_barrier();

  // ---- epilogue: bias + skip, classifier partials (Wc from global, Y from LDS)
  float wsum[4][7] = {};
#pragma unroll
  for (int j = 0; j < 16; ++j) {
    int col = j * 16 + l15;
    float bb = brel[col] + bskip[col];
#pragma unroll
    for (int r = 0; r < 4; ++r) {
      int rl = w * 16 + quad * 4 + r;
      float z = acc[j][r] + bb + bf2f(SH[rl * 256 + col]);
#pragma unroll
      for (int c = 0; c < 7; ++c) wsum[r][c] += z * Wcls[col * 7 + c];
    }
  }
  // reduce over the 16 lanes of each quad (cols) -> every lane holds full row dots
#pragma unroll
  for (int o = 1; o < 16; o <<= 1)
#pragma unroll
    for (int r = 0; r < 4; ++r)
#pragma unroll
      for (int c = 0; c < 7; ++c) wsum[r][c] += __shfl_xor(wsum[r][c], o, 64);

  float lsum = 0.f;
#pragma unroll
  for (int r = 0; r < 4; ++r) {
    int row = m0 + w * 16 + quad * 4 + r;
    float o7[7], mx = -1e30f;
#pragma unroll
    for (int c = 0; c < 7; ++c) {
      o7[c] = wsum[r][c] + bcls[c];
      mx = fmaxf(mx, o7[c]);
    }
    if (l15 < 7) out[(size_t)row * 7 + l15] = o7[l15];
    float s = 0.f;
#pragma unroll
    for (int c = 0; c < 7; ++c) s += expf(o7[c] - mx);
    int lab = labels[row];
    lsum += mx + logf(s) - o7[lab];
  }
  // quad-totals are lane-identical; combine the 4 quads
  lsum += __shfl_xor(lsum, 16, 64);
  lsum += __shfl_xor(lsum, 32, 64);
  if (lane == 0) atomicAdd(loss, lsum * (1.0f / (float)NN));
#undef G2_STAGE
#undef G2_COMPUTE
}

extern "C" void kernel_launch(void* const* d_in, const int* in_sizes, int n_in,
                              void* d_out, int out_size, void* d_ws, size_t ws_size,
                              hipStream_t stream) {
  const float* x      = (const float*)d_in[0];
  const int* speakers = (const int*)d_in[2];
  const int* labels   = (const int*)d_in[3];
  const float* Wrgcn  = (const float*)d_in[6];
  const float* Wroot  = (const float*)d_in[7];
  const float* brgcn  = (const float*)d_in[8];
  const float* Wrel   = (const float*)d_in[9];
  const float* brel   = (const float*)d_in[10];
  const float* Wgrt   = (const float*)d_in[11];
  const float* Wskip  = (const float*)d_in[12];
  const float* bskip  = (const float*)d_in[13];
  const float* Wcls   = (const float*)d_in[14];
  const float* bcls   = (const float*)d_in[15];
  float* out = (float*)d_out;
  float* loss = out + (size_t)NN * 7;

  // workspace layout (bytes)
  const size_t OFF_XBF  = 0;                  // 67,108,864  (bf16 X)
  const size_t OFF_WBIG = 67108864;           //  2,097,152
  const size_t OFF_WSM  = 69206016;           //    262,144
  const size_t OFF_Y    = 69468160;           // 67,108,864  (bf16 [Y0|Y1|Yroot|Yskip])
  const size_t OFF_A2   = 136577024;          // 33,554,432  (bf16 [h|neigh])
  const size_t NEED     = 170131456;
  if (ws_size < NEED) return;

  char* ws = (char*)d_ws;
  unsigned short* Xbf   = (unsigned short*)(ws + OFF_XBF);
  unsigned short* WbigT = (unsigned short*)(ws + OFF_WBIG);
  unsigned short* WsmT  = (unsigned short*)(ws + OFF_WSM);
  unsigned short* Y     = (unsigned short*)(ws + OFF_Y);
  unsigned short* A2    = (unsigned short*)(ws + OFF_A2);

  diagcn_prep<<<dim3(16672), dim3(256), 0, stream>>>(x, Wrgcn, Wroot, Wskip, Wgrt, Wrel,
                                                     Xbf, WbigT, WsmT, loss);
  diagcn_gemm1<<<dim3(512), dim3(512), 0, stream>>>(Xbf, WbigT, Y);
  diagcn_h<<<dim3(NN / 8), dim3(256), 0, stream>>>(Y, speakers, brgcn, A2);
  diagcn_neigh<<<dim3(NN / 8), dim3(256), 0, stream>>>(A2);
  diagcn_gemm2<<<dim3(512), dim3(256), 0, stream>>>(A2, WsmT, Y, Wcls, bcls, brel, bskip,
                                                    labels, out, loss);
}

// Round 11
// 361.946 us; speedup vs baseline: 1.1341x; 1.0251x over previous
//
#include <hip/hip_runtime.h>

// Problem constants (fixed by reference): B=128, L=256, F=P=4, IN=1024, H=256, C=7
#define NN 32768        // N = B*L
#define INF 1024
#define HF 256

typedef __bf16 bf16x8 __attribute__((ext_vector_type(8)));
typedef float f32x4 __attribute__((ext_vector_type(4)));
typedef unsigned short u16x8 __attribute__((ext_vector_type(8)));

__device__ __forceinline__ float bf2f(unsigned short u) {
  union { unsigned int i; float f; } v; v.i = ((unsigned int)u) << 16; return v.f;
}
__device__ __forceinline__ unsigned short f2bf(float f) {
  union { float f; unsigned int i; } v; v.f = f;
  unsigned int x = v.i;
  return (unsigned short)((x + 0x7fffu + ((x >> 16) & 1u)) >> 16);  // RNE
}

// async global->LDS, 16B per lane; SOURCE is per-lane, DEST = uniform base + lane*16
__device__ __forceinline__ void ld_lds16(const unsigned short* g, unsigned short* l) {
  __builtin_amdgcn_global_load_lds(
      (__attribute__((address_space(1))) const unsigned int*)g,
      (__attribute__((address_space(3))) unsigned int*)l, 16, 0, 0);
}
__device__ __forceinline__ void ld_lds16v(const void* g, void* l) {
  __builtin_amdgcn_global_load_lds(
      (__attribute__((address_space(1))) const unsigned int*)g,
      (__attribute__((address_space(3))) unsigned int*)l, 16, 0, 0);
}

// pack 8 fp32 -> bf16x8 via v_cvt_pk_bf16_f32 (RNE; bit-matches f2bf on normals)
__device__ __forceinline__ bf16x8 cvt8(f32x4 lo, f32x4 hi) {
  union { unsigned int u[4]; bf16x8 v; } r;
  asm("v_cvt_pk_bf16_f32 %0, %1, %2" : "=v"(r.u[0]) : "v"(lo[0]), "v"(lo[1]));
  asm("v_cvt_pk_bf16_f32 %0, %1, %2" : "=v"(r.u[1]) : "v"(lo[2]), "v"(lo[3]));
  asm("v_cvt_pk_bf16_f32 %0, %1, %2" : "=v"(r.u[2]) : "v"(hi[0]), "v"(hi[1]));
  asm("v_cvt_pk_bf16_f32 %0, %1, %2" : "=v"(r.u[3]) : "v"(hi[2]), "v"(hi[3]));
  return r.v;
}

// ---- prep (weights only): 288 blocks, 64x64 LDS transpose (coalesced both sides)
// WbigT[n][k] (1024x1024) = [W0|W1|Wroot|Wskip]^T ; WsmT[n][k] (256x512) = [Wgrt;Wrel]^T
// X is consumed as fp32 DIRECTLY by gemm1 (saves the 192 MB Xbf round trip).
__global__ __launch_bounds__(256)
void diagcn_prep(const float* __restrict__ Wrgcn, const float* __restrict__ Wroot,
                 const float* __restrict__ Wskip, const float* __restrict__ Wgrt,
                 const float* __restrict__ Wrel, unsigned short* __restrict__ WbigT,
                 unsigned short* __restrict__ WsmT, float* __restrict__ loss) {
  int tb = blockIdx.x;
  if (tb == 0 && threadIdx.x == 0) loss[0] = 0.f;
  __shared__ float tile[64 * 65];
  const float* src;
  int k0, ncol0;
  unsigned short* dst;
  int ldd, nrow0;
  if (tb < 256) {            // WbigT tiles: tn 0..15, tk 0..15
    int tn = tb >> 4, tk = tb & 15;
    int mat = tn >> 2;
    src = (mat == 0) ? Wrgcn : (mat == 1) ? (Wrgcn + 262144) : (mat == 2) ? Wroot : Wskip;
    k0 = tk * 64; ncol0 = (tn & 3) * 64;
    dst = WbigT; ldd = 1024; nrow0 = tn * 64;
  } else {                   // WsmT tiles: tn 0..3, tk 0..7
    int t2 = tb - 256;
    int tn = t2 >> 3, tk = t2 & 7;
    src = (tk < 4) ? Wgrt : Wrel;
    k0 = (tk & 3) * 64; ncol0 = tn * 64;
    dst = WsmT; ldd = 512; nrow0 = tn * 64;
  }
  int kdst0 = (tb < 256) ? k0 : (((tb - 256) & 7) * 64);
  int c = threadIdx.x & 63, rb = threadIdx.x >> 6;
#pragma unroll
  for (int it = 0; it < 16; ++it) {
    int r = rb + it * 4;
    tile[r * 65 + c] = src[(size_t)(k0 + r) * 256 + ncol0 + c];
  }
  __syncthreads();
  int kk = threadIdx.x & 63;
#pragma unroll
  for (int it = 0; it < 16; ++it) {
    int nn = rb + it * 4;
    dst[(size_t)(nrow0 + nn) * ldd + kdst0 + kk] = f2bf(tile[kk * 65 + nn]);
  }
}

// ---- GEMM1 v6: Y[32768 x 1024] = bf16(X) @ WbigT^T, fp32 X staged DIRECTLY.
// 256x256 tile, 512 threads (8 waves 2m x 4n -> 128x64/wave), BK=32.
// Triple-buffered LDS: 3 x (A-fp32 32KB + B-bf16 16KB) = 144 KB, 1 block/CU.
// Counted pipeline (R2 shape preserved): 6 global_load_lds per thread per tile
// (A 4 + B 2), prefetch depth 2, per-tile gate vmcnt(6), vmcnt(0) only at tail.
// A swizzle: row = 128B = 8 chunks; stored[row][c] = src[row][c ^ (row&7)]
// (same 8-chunk XOR family gemm2 measures at 0 bank conflicts). Source addr is
// pre-swizzled per-lane; LDS dest stays linear (global_load_lds requirement).
// LDS->reg: 2 x ds_read_b128 fp32 per A-frag + cvt_pk -> bf16x8 (RNE = f2bf),
// register-dep chain so the compiler inserts exact lgkm waits (no manual gates).
__global__ __launch_bounds__(512, 1)
void diagcn_gemm1(const float* __restrict__ X, const unsigned short* __restrict__ BT,
                  unsigned short* __restrict__ Y) {
  __shared__ unsigned short SH[73728];   // 144 KB: 3 bufs x (A 16384 + B 8192 elems)
  const int tid = threadIdx.x;
  const int w = tid >> 6, lane = tid & 63;
  const int quad = lane >> 4, l15 = lane & 15;
  const int wm = w >> 2, wn = w & 3;
  const int b = blockIdx.x;
  // XCD-aware bijective swizzle: 512 blocks = 8 XCDs x 64; n fastest within XCD
  const int wg = ((b & 7) << 6) + (b >> 3);
  const int m0 = (wg >> 2) << 8;
  const int n0 = (wg & 3) << 8;
  const int bbase = wn * 64 + l15;                        // wave B-row base
  const int sw8 = ((quad ^ ((l15 >> 1) & 3)) << 3);       // B read-side swizzle
  const int csrc8 = (((lane & 3) ^ ((lane >> 3) & 3)) << 3); // B source-side swizzle
  // A fp32: source row m0 + w*32 + (lane>>3), chunk (lane&7)^(lane>>3)
  const float* gAf = X + (size_t)(m0 + w * 32 + (lane >> 3)) * 1024
                       + (((lane & 7) ^ (lane >> 3)) << 2);
  const unsigned short* gB0 = BT + (size_t)(n0 + w * 32 + (lane >> 2)) * 1024 + csrc8;
  // A read-side: src chunk 2q at stored chunk (2q)^(l15&7); partner = ^1 chunk
  const int c1o = (((2 * quad) ^ (l15 & 7)) << 2);        // float offset
  const int c2o = c1o ^ 4;

  f32x4 acc[8][4] = {};

#define G1_STAGE(t, buf)                                                       \
  {                                                                            \
    unsigned short* aB = SH + (buf) * 24576 + w * 2048;                        \
    const float* gs = gAf + (t) * 32;                                          \
    ld_lds16v(gs,             aB);                                             \
    ld_lds16v(gs +  8 * 1024, aB +  512);                                      \
    ld_lds16v(gs + 16 * 1024, aB + 1024);                                      \
    ld_lds16v(gs + 24 * 1024, aB + 1536);                                      \
    unsigned short* bB = SH + (buf) * 24576 + 16384 + w * 1024;                \
    const unsigned short* gb = gB0 + (t) * 32;                                 \
    ld_lds16(gb, bB);                                                          \
    ld_lds16(gb + 16 * 1024, bB + 512);                                        \
  }

#define G1_COMPUTE(buf)                                                       \
  {                                                                           \
    const float* Af = (const float*)(SH + (buf) * 24576);                     \
    const unsigned short* Bs = SH + (buf) * 24576 + 16384;                    \
    bf16x8 bv[4];                                                             \
    _Pragma("unroll")                                                         \
    for (int j = 0; j < 4; ++j)                                               \
      bv[j] = *(const bf16x8*)&Bs[(bbase + j * 16) * 32 + sw8];               \
    __builtin_amdgcn_s_setprio(1);                                            \
    _Pragma("unroll")                                                         \
    for (int i = 0; i < 8; ++i) {                                             \
      int ra = wm * 128 + i * 16 + l15;                                       \
      const float* rp = Af + ra * 32;                                         \
      f32x4 lo = *(const f32x4*)(rp + c1o);                                   \
      f32x4 hi = *(const f32x4*)(rp + c2o);                                   \
      bf16x8 av = cvt8(lo, hi);                                               \
      _Pragma("unroll")                                                       \
      for (int j = 0; j < 4; ++j)                                             \
        acc[i][j] = __builtin_amdgcn_mfma_f32_16x16x32_bf16(av, bv[j], acc[i][j], 0, 0, 0); \
    }                                                                         \
    __builtin_amdgcn_s_setprio(0);                                            \
  }

  // prologue: stage tiles 0,1 (12 loads/thread in flight)
  G1_STAGE(0, 0);
  G1_STAGE(1, 1);
  asm volatile("s_waitcnt vmcnt(6)" ::: "memory");   // tile 0 landed
  __builtin_amdgcn_s_barrier();

#pragma unroll 1
  for (int t = 0; t < 30; ++t) {
    G1_STAGE(t + 2, (t + 2) % 3);                    // into buf of tile t-1 (drained)
    G1_COMPUTE(t % 3);
    asm volatile("s_waitcnt vmcnt(6)" ::: "memory"); // tile t+1 landed; t+2 in flight
    __builtin_amdgcn_s_barrier();                    // collectivize + WAR fence
  }
  G1_COMPUTE(0);                                     // tile 30 (30%3=0)
  asm volatile("s_waitcnt vmcnt(0)" ::: "memory");   // tile 31 landed (tail only)
  __builtin_amdgcn_s_barrier();
  G1_COMPUTE(1);                                     // tile 31 (31%3=1)
#undef G1_STAGE
#undef G1_COMPUTE

  // epilogue: C/D mapping col=lane&15, row=quad*4+r
#pragma unroll
  for (int i = 0; i < 8; ++i)
#pragma unroll
    for (int j = 0; j < 4; ++j) {
      const int row = m0 + wm * 128 + i * 16 + quad * 4;
      const int col = n0 + wn * 64 + j * 16 + l15;
#pragma unroll
      for (int r = 0; r < 4; ++r)
        Y[(size_t)(row + r) * 1024 + col] = f2bf(acc[i][j][r]);
    }
}

// ---- RGCN aggregate, 2 nodes per wave (8 ch/lane, 16B loads), branchless window.
// h_i = Yroot_i + b + sum_r mean_{j in win, rel=r} Y_r[j]; bf16 h -> A2[:,0:256].
__global__ __launch_bounds__(256)
void diagcn_h(const unsigned short* __restrict__ Y, const int* __restrict__ spk,
              const float* __restrict__ brgcn, unsigned short* __restrict__ A2) {
  int b = blockIdx.x;
  int wv = threadIdx.x >> 6, lane = threadIdx.x & 63;
  int half = lane >> 5, li = lane & 31, c0 = li << 3;
  int node = ((b & 7) << 12) + ((b >> 3) << 3) + wv * 2 + half;
  int p = node & 255, dbase = node - p;
  int si = spk[node];
  float a0[8] = {}, a1[8] = {};
  float n0 = 0.f, n1 = 0.f;
#pragma unroll
  for (int d = -4; d <= 4; ++d) {
    int pj = p + d;
    float w = (pj >= 0 && pj < 256) ? 1.f : 0.f;
    int jc = pj < 0 ? 0 : (pj > 255 ? 255 : pj);
    int nj = dbase + jc;
    int rel = si & spk[nj];
    u16x8 v = *(const u16x8*)&Y[(size_t)nj * 1024 + (rel << 8) + c0];
    float w1 = rel ? w : 0.f, w0 = rel ? 0.f : w;
#pragma unroll
    for (int k = 0; k < 8; ++k) {
      float f = bf2f(v[k]);
      a0[k] += f * w0; a1[k] += f * w1;
    }
    n0 += w0; n1 += w1;
  }
  u16x8 vr = *(const u16x8*)&Y[(size_t)node * 1024 + 512 + c0];
  float i0 = 1.f / fmaxf(n0, 1.f), i1 = 1.f / fmaxf(n1, 1.f);
  u16x8 u;
#pragma unroll
  for (int k = 0; k < 8; ++k)
    u[k] = f2bf(bf2f(vr[k]) + brgcn[c0 + k] + a0[k] * i0 + a1[k] * i1);
  *(u16x8*)&A2[(size_t)node * 512 + c0] = u;
}

// ---- GraphConv neighbor sum (aggr=add over window incl. self), 2 nodes/wave.
__global__ __launch_bounds__(256)
void diagcn_neigh(unsigned short* __restrict__ A2) {
  int b = blockIdx.x;
  int wv = threadIdx.x >> 6, lane = threadIdx.x & 63;
  int half = lane >> 5, li = lane & 31, c0 = li << 3;
  int node = ((b & 7) << 12) + ((b >> 3) << 3) + wv * 2 + half;
  int p = node & 255, dbase = node - p;
  float s[8] = {};
#pragma unroll
  for (int d = -4; d <= 4; ++d) {
    int pj = p + d;
    float w = (pj >= 0 && pj < 256) ? 1.f : 0.f;
    int jc = pj < 0 ? 0 : (pj > 255 ? 255 : pj);
    u16x8 v = *(const u16x8*)&A2[(size_t)(dbase + jc) * 512 + c0];
#pragma unroll
    for (int k = 0; k < 8; ++k) s[k] += bf2f(v[k]) * w;
  }
  u16x8 u;
#pragma unroll
  for (int k = 0; k < 8; ++k) u[k] = f2bf(s[k]);
  *(u16x8*)&A2[(size_t)node * 512 + 256 + c0] = u;
}

// ---- GEMM2 v3 + fused epilogue (R10-measured: counted double-buffer pipeline).
__global__ __launch_bounds__(256)
void diagcn_gemm2(const unsigned short* __restrict__ A, const unsigned short* __restrict__ BT,
                  const unsigned short* __restrict__ Y, const float* __restrict__ Wcls,
                  const float* __restrict__ bcls, const float* __restrict__ brel,
                  const float* __restrict__ bskip, const int* __restrict__ labels,
                  float* __restrict__ out, float* __restrict__ loss) {
  const int K = 512;
  __shared__ unsigned short SH[40960];   // 80 KB: 2 bufs x (A 4096 + B 16384 elems)
  const int tid = threadIdx.x;
  const int w = tid >> 6, lane = tid & 63;
  const int quad = lane >> 4, l15 = lane & 15;
  const int b = blockIdx.x;
  const int m0 = (((b & 7) << 6) + (b >> 3)) << 6;   // 512 m-tiles of 64 rows
  const int rowg = lane >> 3;
  const int kbsw = (lane & 7) ^ rowg;

  f32x4 acc[16] = {};
  const unsigned short* Abase = A + (size_t)m0 * K + kbsw * 8;
  const unsigned short* Bbase = BT + kbsw * 8;
  const unsigned short* Ybase = Y + (size_t)(m0 + (lane >> 5)) * 1024 + 768 + (lane & 31) * 8;

#define G2_STAGE(t, buf)                                                        \
  {                                                                             \
    unsigned short* As_ = SH + (buf) * 20480;                                   \
    unsigned short* Bs_ = As_ + 4096;                                           \
    int k0_ = (t) * 64;                                                         \
    _Pragma("unroll")                                                           \
    for (int i = 0; i < 2; ++i) {                                               \
      int grp = w * 2 + i;                                                      \
      ld_lds16(Abase + (size_t)(grp * 8 + rowg) * K + k0_, &As_[grp * 512]);    \
    }                                                                           \
    _Pragma("unroll")                                                           \
    for (int i = 0; i < 8; ++i) {                                               \
      int grp = w * 8 + i;                                                      \
      ld_lds16(Bbase + (size_t)(grp * 8 + rowg) * K + k0_, &Bs_[grp * 512]);    \
    }                                                                           \
  }
#define G2_COMPUTE(buf)                                                         \
  {                                                                             \
    const unsigned short* As_ = SH + (buf) * 20480;                             \
    const unsigned short* Bs_ = As_ + 4096;                                     \
    _Pragma("unroll")                                                           \
    for (int ks = 0; ks < 2; ++ks) {                                            \
      int kb = ks * 4 + quad;                                                   \
      int ra = w * 16 + l15;                                                    \
      bf16x8 av = *(const bf16x8*)&As_[ra * 64 + ((kb ^ (ra & 7)) << 3)];       \
      _Pragma("unroll")                                                         \
      for (int j = 0; j < 16; ++j) {                                            \
        int rb2 = j * 16 + l15;                                                 \
        bf16x8 bv = *(const bf16x8*)&Bs_[rb2 * 64 + ((kb ^ (rb2 & 7)) << 3)];   \
        acc[j] = __builtin_amdgcn_mfma_f32_16x16x32_bf16(av, bv, acc[j], 0, 0, 0); \
      }                                                                         \
    }                                                                           \
  }

  G2_STAGE(0, 0);
  G2_STAGE(1, 1);
  asm volatile("s_waitcnt vmcnt(10)" ::: "memory");   // tile 0 landed
  __builtin_amdgcn_s_barrier();

#pragma unroll 1
  for (int t = 0; t < 6; ++t) {
    G2_COMPUTE(t & 1);
    asm volatile("s_waitcnt lgkmcnt(0)" ::: "memory");
    __builtin_amdgcn_s_barrier();
    G2_STAGE(t + 2, t & 1);
    asm volatile("s_waitcnt vmcnt(10)" ::: "memory");
    __builtin_amdgcn_s_barrier();
  }
  G2_COMPUTE(0);                                       // tile 6
  asm volatile("s_waitcnt lgkmcnt(0)" ::: "memory");
  __builtin_amdgcn_s_barrier();
  asm volatile("s_waitcnt vmcnt(0)" ::: "memory");     // tile 7 landed
  __builtin_amdgcn_s_barrier();
#pragma unroll
  for (int i = 0; i < 8; ++i) {
    int g = w * 8 + i;
    ld_lds16(Ybase + (size_t)g * 2048, &SH[g * 512]);  // Y-skip tile into freed buf0
  }
  G2_COMPUTE(1);                                       // tile 7
  asm volatile("s_waitcnt vmcnt(0)" ::: "memory");     // Y landed
  __builtin_amdgcn_s_barrier();

  float wsum[4][7] = {};
#pragma unroll
  for (int j = 0; j < 16; ++j) {
    int col = j * 16 + l15;
    float bb = brel[col] + bskip[col];
#pragma unroll
    for (int r = 0; r < 4; ++r) {
      int rl = w * 16 + quad * 4 + r;
      float z = acc[j][r] + bb + bf2f(SH[rl * 256 + col]);
#pragma unroll
      for (int c = 0; c < 7; ++c) wsum[r][c] += z * Wcls[col * 7 + c];
    }
  }
#pragma unroll
  for (int o = 1; o < 16; o <<= 1)
#pragma unroll
    for (int r = 0; r < 4; ++r)
#pragma unroll
      for (int c = 0; c < 7; ++c) wsum[r][c] += __shfl_xor(wsum[r][c], o, 64);

  float lsum = 0.f;
#pragma unroll
  for (int r = 0; r < 4; ++r) {
    int row = m0 + w * 16 + quad * 4 + r;
    float o7[7], mx = -1e30f;
#pragma unroll
    for (int c = 0; c < 7; ++c) {
      o7[c] = wsum[r][c] + bcls[c];
      mx = fmaxf(mx, o7[c]);
    }
    if (l15 < 7) out[(size_t)row * 7 + l15] = o7[l15];
    float s = 0.f;
#pragma unroll
    for (int c = 0; c < 7; ++c) s += expf(o7[c] - mx);
    int lab = labels[row];
    lsum += mx + logf(s) - o7[lab];
  }
  lsum += __shfl_xor(lsum, 16, 64);
  lsum += __shfl_xor(lsum, 32, 64);
  if (lane == 0) atomicAdd(loss, lsum * (1.0f / (float)NN));
#undef G2_STAGE
#undef G2_COMPUTE
}

extern "C" void kernel_launch(void* const* d_in, const int* in_sizes, int n_in,
                              void* d_out, int out_size, void* d_ws, size_t ws_size,
                              hipStream_t stream) {
  const float* x      = (const float*)d_in[0];
  const int* speakers = (const int*)d_in[2];
  const int* labels   = (const int*)d_in[3];
  const float* Wrgcn  = (const float*)d_in[6];
  const float* Wroot  = (const float*)d_in[7];
  const float* brgcn  = (const float*)d_in[8];
  const float* Wrel   = (const float*)d_in[9];
  const float* brel   = (const float*)d_in[10];
  const float* Wgrt   = (const float*)d_in[11];
  const float* Wskip  = (const float*)d_in[12];
  const float* bskip  = (const float*)d_in[13];
  const float* Wcls   = (const float*)d_in[14];
  const float* bcls   = (const float*)d_in[15];
  float* out = (float*)d_out;
  float* loss = out + (size_t)NN * 7;

  // workspace layout (bytes) — Xbf eliminated (X read as fp32 by gemm1)
  const size_t OFF_WBIG = 0;                  //  2,097,152
  const size_t OFF_WSM  = 2097152;            //    262,144
  const size_t OFF_Y    = 2359296;            // 67,108,864  (bf16 [Y0|Y1|Yroot|Yskip])
  const size_t OFF_A2   = 69468160;           // 33,554,432  (bf16 [h|neigh])
  const size_t NEED     = 103022592;
  if (ws_size < NEED) return;

  char* ws = (char*)d_ws;
  unsigned short* WbigT = (unsigned short*)(ws + OFF_WBIG);
  unsigned short* WsmT  = (unsigned short*)(ws + OFF_WSM);
  unsigned short* Y     = (unsigned short*)(ws + OFF_Y);
  unsigned short* A2    = (unsigned short*)(ws + OFF_A2);

  diagcn_prep<<<dim3(288), dim3(256), 0, stream>>>(Wrgcn, Wroot, Wskip, Wgrt, Wrel,
                                                   WbigT, WsmT, loss);
  diagcn_gemm1<<<dim3(512), dim3(512), 0, stream>>>(x, WbigT, Y);
  diagcn_h<<<dim3(NN / 8), dim3(256), 0, stream>>>(Y, speakers, brgcn, A2);
  diagcn_neigh<<<dim3(NN / 8), dim3(256), 0, stream>>>(A2);
  diagcn_gemm2<<<dim3(512), dim3(256), 0, stream>>>(A2, WsmT, Y, Wcls, bcls, brel, bskip,
                                                    labels, out, loss);
}

// Round 12
// 361.770 us; speedup vs baseline: 1.1347x; 1.0005x over previous
//
#include <hip/hip_runtime.h>

// Problem constants (fixed by reference): B=128, L=256, F=P=4, IN=1024, H=256, C=7
#define NN 32768        // N = B*L
#define INF 1024
#define HF 256

typedef __bf16 bf16x8 __attribute__((ext_vector_type(8)));
typedef float f32x4 __attribute__((ext_vector_type(4)));
typedef unsigned short u16x8 __attribute__((ext_vector_type(8)));

__device__ __forceinline__ float bf2f(unsigned short u) {
  union { unsigned int i; float f; } v; v.i = ((unsigned int)u) << 16; return v.f;
}
__device__ __forceinline__ unsigned short f2bf(float f) {
  union { float f; unsigned int i; } v; v.f = f;
  unsigned int x = v.i;
  return (unsigned short)((x + 0x7fffu + ((x >> 16) & 1u)) >> 16);  // RNE
}

// async global->LDS, 16B per lane; SOURCE is per-lane, DEST = uniform base + lane*16
__device__ __forceinline__ void ld_lds16(const unsigned short* g, unsigned short* l) {
  __builtin_amdgcn_global_load_lds(
      (__attribute__((address_space(1))) const unsigned int*)g,
      (__attribute__((address_space(3))) unsigned int*)l, 16, 0, 0);
}
__device__ __forceinline__ void ld_lds16v(const void* g, void* l) {
  __builtin_amdgcn_global_load_lds(
      (__attribute__((address_space(1))) const unsigned int*)g,
      (__attribute__((address_space(3))) unsigned int*)l, 16, 0, 0);
}

// pack 8 fp32 -> bf16x8 via v_cvt_pk_bf16_f32 (RNE; bit-matches f2bf on normals)
__device__ __forceinline__ bf16x8 cvt8(f32x4 lo, f32x4 hi) {
  union { unsigned int u[4]; bf16x8 v; } r;
  asm("v_cvt_pk_bf16_f32 %0, %1, %2" : "=v"(r.u[0]) : "v"(lo[0]), "v"(lo[1]));
  asm("v_cvt_pk_bf16_f32 %0, %1, %2" : "=v"(r.u[1]) : "v"(lo[2]), "v"(lo[3]));
  asm("v_cvt_pk_bf16_f32 %0, %1, %2" : "=v"(r.u[2]) : "v"(hi[0]), "v"(hi[1]));
  asm("v_cvt_pk_bf16_f32 %0, %1, %2" : "=v"(r.u[3]) : "v"(hi[2]), "v"(hi[3]));
  return r.v;
}

// ---- prep (weights only): 288 blocks, 64x64 LDS transpose (coalesced both sides)
// WbigT[n][k] (1024x1024) = [W0|W1|Wroot|Wskip]^T ; WsmT[n][k] (256x512) = [Wgrt;Wrel]^T
// X is consumed as fp32 DIRECTLY by gemm1 (saves the 192 MB Xbf round trip).
__global__ __launch_bounds__(256)
void diagcn_prep(const float* __restrict__ Wrgcn, const float* __restrict__ Wroot,
                 const float* __restrict__ Wskip, const float* __restrict__ Wgrt,
                 const float* __restrict__ Wrel, unsigned short* __restrict__ WbigT,
                 unsigned short* __restrict__ WsmT, float* __restrict__ loss) {
  int tb = blockIdx.x;
  if (tb == 0 && threadIdx.x == 0) loss[0] = 0.f;
  __shared__ float tile[64 * 65];
  const float* src;
  int k0, ncol0;
  unsigned short* dst;
  int ldd, nrow0;
  if (tb < 256) {            // WbigT tiles: tn 0..15, tk 0..15
    int tn = tb >> 4, tk = tb & 15;
    int mat = tn >> 2;
    src = (mat == 0) ? Wrgcn : (mat == 1) ? (Wrgcn + 262144) : (mat == 2) ? Wroot : Wskip;
    k0 = tk * 64; ncol0 = (tn & 3) * 64;
    dst = WbigT; ldd = 1024; nrow0 = tn * 64;
  } else {                   // WsmT tiles: tn 0..3, tk 0..7
    int t2 = tb - 256;
    int tn = t2 >> 3, tk = t2 & 7;
    src = (tk < 4) ? Wgrt : Wrel;
    k0 = (tk & 3) * 64; ncol0 = tn * 64;
    dst = WsmT; ldd = 512; nrow0 = tn * 64;
  }
  int kdst0 = (tb < 256) ? k0 : (((tb - 256) & 7) * 64);
  int c = threadIdx.x & 63, rb = threadIdx.x >> 6;
#pragma unroll
  for (int it = 0; it < 16; ++it) {
    int r = rb + it * 4;
    tile[r * 65 + c] = src[(size_t)(k0 + r) * 256 + ncol0 + c];
  }
  __syncthreads();
  int kk = threadIdx.x & 63;
#pragma unroll
  for (int it = 0; it < 16; ++it) {
    int nn = rb + it * 4;
    dst[(size_t)(nrow0 + nn) * ldd + kdst0 + kk] = f2bf(tile[kk * 65 + nn]);
  }
}

// ---- GEMM1 v7: Y[32768 x 1024] = bf16(X) @ WbigT^T, fp32 X staged DIRECTLY.
// 256x256 tile, 512 threads; wave grid 4m x 2n (64x128 per wave) -- reshaped from
// 2m x 4n to cut LDS read traffic: A frag-reads 128->64 KB/tile (fp32 frags are
// 32B/lane, redundancy 4->2 waves), B 32->64 KB (bf16 16B frags) = net -32 KB/tile
// and cvt_pk work halved (R11 counters: LDS-bound, 8.4M bank-conflict cycles).
// Triple-buffered LDS: 3 x (A-fp32 32KB + B-bf16 16KB) = 144 KB, 1 block/CU.
// Counted pipeline (unchanged from R11): 6 global_load_lds per thread per tile,
// prefetch depth 2, per-tile gate vmcnt(6), vmcnt(0) only at tail.
__global__ __launch_bounds__(512, 1)
void diagcn_gemm1(const float* __restrict__ X, const unsigned short* __restrict__ BT,
                  unsigned short* __restrict__ Y) {
  __shared__ unsigned short SH[73728];   // 144 KB: 3 bufs x (A 16384 + B 8192 elems)
  const int tid = threadIdx.x;
  const int w = tid >> 6, lane = tid & 63;
  const int quad = lane >> 4, l15 = lane & 15;
  const int wm = w >> 1, wn = w & 1;     // 4m x 2n wave grid
  const int b = blockIdx.x;
  // XCD-aware bijective swizzle: 512 blocks = 8 XCDs x 64; n fastest within XCD
  const int wg = ((b & 7) << 6) + (b >> 3);
  const int m0 = (wg >> 2) << 8;
  const int n0 = (wg & 3) << 8;
  const int bbase = wn * 128 + l15;                       // wave B-row base (j*16 added)
  const int sw8 = ((quad ^ ((l15 >> 1) & 3)) << 3);       // B read-side swizzle
  const int csrc8 = (((lane & 3) ^ ((lane >> 3) & 3)) << 3); // B source-side swizzle
  // A fp32: source row m0 + w*32 + (lane>>3), chunk (lane&7)^(lane>>3)
  const float* gAf = X + (size_t)(m0 + w * 32 + (lane >> 3)) * 1024
                       + (((lane & 7) ^ (lane >> 3)) << 2);
  const unsigned short* gB0 = BT + (size_t)(n0 + w * 32 + (lane >> 2)) * 1024 + csrc8;
  // A read-side: src chunk 2q at stored chunk (2q)^(l15&7); partner = ^1 chunk
  const int c1o = (((2 * quad) ^ (l15 & 7)) << 2);        // float offset
  const int c2o = c1o ^ 4;

  f32x4 acc[4][8] = {};

#define G1_STAGE(t, buf)                                                       \
  {                                                                            \
    unsigned short* aB = SH + (buf) * 24576 + w * 2048;                        \
    const float* gs = gAf + (t) * 32;                                          \
    ld_lds16v(gs,             aB);                                             \
    ld_lds16v(gs +  8 * 1024, aB +  512);                                      \
    ld_lds16v(gs + 16 * 1024, aB + 1024);                                      \
    ld_lds16v(gs + 24 * 1024, aB + 1536);                                      \
    unsigned short* bB = SH + (buf) * 24576 + 16384 + w * 1024;                \
    const unsigned short* gb = gB0 + (t) * 32;                                 \
    ld_lds16(gb, bB);                                                          \
    ld_lds16(gb + 16 * 1024, bB + 512);                                        \
  }

#define G1_COMPUTE(buf)                                                       \
  {                                                                           \
    const float* Af = (const float*)(SH + (buf) * 24576);                     \
    const unsigned short* Bs = SH + (buf) * 24576 + 16384;                    \
    bf16x8 bv[8];                                                             \
    _Pragma("unroll")                                                         \
    for (int j = 0; j < 8; ++j)                                               \
      bv[j] = *(const bf16x8*)&Bs[(bbase + j * 16) * 32 + sw8];               \
    __builtin_amdgcn_s_setprio(1);                                            \
    _Pragma("unroll")                                                         \
    for (int i = 0; i < 4; ++i) {                                             \
      int ra = wm * 64 + i * 16 + l15;                                        \
      const float* rp = Af + ra * 32;                                         \
      f32x4 lo = *(const f32x4*)(rp + c1o);                                   \
      f32x4 hi = *(const f32x4*)(rp + c2o);                                   \
      bf16x8 av = cvt8(lo, hi);                                               \
      _Pragma("unroll")                                                       \
      for (int j = 0; j < 8; ++j)                                             \
        acc[i][j] = __builtin_amdgcn_mfma_f32_16x16x32_bf16(av, bv[j], acc[i][j], 0, 0, 0); \
    }                                                                         \
    __builtin_amdgcn_s_setprio(0);                                            \
  }

  // prologue: stage tiles 0,1 (12 loads/thread in flight)
  G1_STAGE(0, 0);
  G1_STAGE(1, 1);
  asm volatile("s_waitcnt vmcnt(6)" ::: "memory");   // tile 0 landed
  __builtin_amdgcn_s_barrier();

#pragma unroll 1
  for (int t = 0; t < 30; ++t) {
    G1_STAGE(t + 2, (t + 2) % 3);                    // into buf of tile t-1 (drained)
    G1_COMPUTE(t % 3);
    asm volatile("s_waitcnt vmcnt(6)" ::: "memory"); // tile t+1 landed; t+2 in flight
    __builtin_amdgcn_s_barrier();                    // collectivize + WAR fence
  }
  G1_COMPUTE(0);                                     // tile 30 (30%3=0)
  asm volatile("s_waitcnt vmcnt(0)" ::: "memory");   // tile 31 landed (tail only)
  __builtin_amdgcn_s_barrier();
  G1_COMPUTE(1);                                     // tile 31 (31%3=1)
#undef G1_STAGE
#undef G1_COMPUTE

  // epilogue: C/D mapping col=lane&15, row=quad*4+r
#pragma unroll
  for (int i = 0; i < 4; ++i)
#pragma unroll
    for (int j = 0; j < 8; ++j) {
      const int row = m0 + wm * 64 + i * 16 + quad * 4;
      const int col = n0 + wn * 128 + j * 16 + l15;
#pragma unroll
      for (int r = 0; r < 4; ++r)
        Y[(size_t)(row + r) * 1024 + col] = f2bf(acc[i][j][r]);
    }
}

// ---- RGCN aggregate, 2 nodes per wave (8 ch/lane, 16B loads), branchless window.
// h_i = Yroot_i + b + sum_r mean_{j in win, rel=r} Y_r[j]; bf16 h -> A2[:,0:256].
__global__ __launch_bounds__(256)
void diagcn_h(const unsigned short* __restrict__ Y, const int* __restrict__ spk,
              const float* __restrict__ brgcn, unsigned short* __restrict__ A2) {
  int b = blockIdx.x;
  int wv = threadIdx.x >> 6, lane = threadIdx.x & 63;
  int half = lane >> 5, li = lane & 31, c0 = li << 3;
  int node = ((b & 7) << 12) + ((b >> 3) << 3) + wv * 2 + half;
  int p = node & 255, dbase = node - p;
  int si = spk[node];
  float a0[8] = {}, a1[8] = {};
  float n0 = 0.f, n1 = 0.f;
#pragma unroll
  for (int d = -4; d <= 4; ++d) {
    int pj = p + d;
    float w = (pj >= 0 && pj < 256) ? 1.f : 0.f;
    int jc = pj < 0 ? 0 : (pj > 255 ? 255 : pj);
    int nj = dbase + jc;
    int rel = si & spk[nj];
    u16x8 v = *(const u16x8*)&Y[(size_t)nj * 1024 + (rel << 8) + c0];
    float w1 = rel ? w : 0.f, w0 = rel ? 0.f : w;
#pragma unroll
    for (int k = 0; k < 8; ++k) {
      float f = bf2f(v[k]);
      a0[k] += f * w0; a1[k] += f * w1;
    }
    n0 += w0; n1 += w1;
  }
  u16x8 vr = *(const u16x8*)&Y[(size_t)node * 1024 + 512 + c0];
  float i0 = 1.f / fmaxf(n0, 1.f), i1 = 1.f / fmaxf(n1, 1.f);
  u16x8 u;
#pragma unroll
  for (int k = 0; k < 8; ++k)
    u[k] = f2bf(bf2f(vr[k]) + brgcn[c0 + k] + a0[k] * i0 + a1[k] * i1);
  *(u16x8*)&A2[(size_t)node * 512 + c0] = u;
}

// ---- GraphConv neighbor sum (aggr=add over window incl. self), 2 nodes/wave.
__global__ __launch_bounds__(256)
void diagcn_neigh(unsigned short* __restrict__ A2) {
  int b = blockIdx.x;
  int wv = threadIdx.x >> 6, lane = threadIdx.x & 63;
  int half = lane >> 5, li = lane & 31, c0 = li << 3;
  int node = ((b & 7) << 12) + ((b >> 3) << 3) + wv * 2 + half;
  int p = node & 255, dbase = node - p;
  float s[8] = {};
#pragma unroll
  for (int d = -4; d <= 4; ++d) {
    int pj = p + d;
    float w = (pj >= 0 && pj < 256) ? 1.f : 0.f;
    int jc = pj < 0 ? 0 : (pj > 255 ? 255 : pj);
    u16x8 v = *(const u16x8*)&A2[(size_t)(dbase + jc) * 512 + c0];
#pragma unroll
    for (int k = 0; k < 8; ++k) s[k] += bf2f(v[k]) * w;
  }
  u16x8 u;
#pragma unroll
  for (int k = 0; k < 8; ++k) u[k] = f2bf(s[k]);
  *(u16x8*)&A2[(size_t)node * 512 + 256 + c0] = u;
}

// ---- GEMM2 v3 + fused epilogue (R10-measured: counted double-buffer pipeline).
__global__ __launch_bounds__(256)
void diagcn_gemm2(const unsigned short* __restrict__ A, const unsigned short* __restrict__ BT,
                  const unsigned short* __restrict__ Y, const float* __restrict__ Wcls,
                  const float* __restrict__ bcls, const float* __restrict__ brel,
                  const float* __restrict__ bskip, const int* __restrict__ labels,
                  float* __restrict__ out, float* __restrict__ loss) {
  const int K = 512;
  __shared__ unsigned short SH[40960];   // 80 KB: 2 bufs x (A 4096 + B 16384 elems)
  const int tid = threadIdx.x;
  const int w = tid >> 6, lane = tid & 63;
  const int quad = lane >> 4, l15 = lane & 15;
  const int b = blockIdx.x;
  const int m0 = (((b & 7) << 6) + (b >> 3)) << 6;   // 512 m-tiles of 64 rows
  const int rowg = lane >> 3;
  const int kbsw = (lane & 7) ^ rowg;

  f32x4 acc[16] = {};
  const unsigned short* Abase = A + (size_t)m0 * K + kbsw * 8;
  const unsigned short* Bbase = BT + kbsw * 8;
  const unsigned short* Ybase = Y + (size_t)(m0 + (lane >> 5)) * 1024 + 768 + (lane & 31) * 8;

#define G2_STAGE(t, buf)                                                        \
  {                                                                             \
    unsigned short* As_ = SH + (buf) * 20480;                                   \
    unsigned short* Bs_ = As_ + 4096;                                           \
    int k0_ = (t) * 64;                                                         \
    _Pragma("unroll")                                                           \
    for (int i = 0; i < 2; ++i) {                                               \
      int grp = w * 2 + i;                                                      \
      ld_lds16(Abase + (size_t)(grp * 8 + rowg) * K + k0_, &As_[grp * 512]);    \
    }                                                                           \
    _Pragma("unroll")                                                           \
    for (int i = 0; i < 8; ++i) {                                               \
      int grp = w * 8 + i;                                                      \
      ld_lds16(Bbase + (size_t)(grp * 8 + rowg) * K + k0_, &Bs_[grp * 512]);    \
    }                                                                           \
  }
#define G2_COMPUTE(buf)                                                         \
  {                                                                             \
    const unsigned short* As_ = SH + (buf) * 20480;                             \
    const unsigned short* Bs_ = As_ + 4096;                                     \
    _Pragma("unroll")                                                           \
    for (int ks = 0; ks < 2; ++ks) {                                            \
      int kb = ks * 4 + quad;                                                   \
      int ra = w * 16 + l15;                                                    \
      bf16x8 av = *(const bf16x8*)&As_[ra * 64 + ((kb ^ (ra & 7)) << 3)];       \
      _Pragma("unroll")                                                         \
      for (int j = 0; j < 16; ++j) {                                            \
        int rb2 = j * 16 + l15;                                                 \
        bf16x8 bv = *(const bf16x8*)&Bs_[rb2 * 64 + ((kb ^ (rb2 & 7)) << 3)];   \
        acc[j] = __builtin_amdgcn_mfma_f32_16x16x32_bf16(av, bv, acc[j], 0, 0, 0); \
      }                                                                         \
    }                                                                           \
  }

  G2_STAGE(0, 0);
  G2_STAGE(1, 1);
  asm volatile("s_waitcnt vmcnt(10)" ::: "memory");   // tile 0 landed
  __builtin_amdgcn_s_barrier();

#pragma unroll 1
  for (int t = 0; t < 6; ++t) {
    G2_COMPUTE(t & 1);
    asm volatile("s_waitcnt lgkmcnt(0)" ::: "memory");
    __builtin_amdgcn_s_barrier();
    G2_STAGE(t + 2, t & 1);
    asm volatile("s_waitcnt vmcnt(10)" ::: "memory");
    __builtin_amdgcn_s_barrier();
  }
  G2_COMPUTE(0);                                       // tile 6
  asm volatile("s_waitcnt lgkmcnt(0)" ::: "memory");
  __builtin_amdgcn_s_barrier();
  asm volatile("s_waitcnt vmcnt(0)" ::: "memory");     // tile 7 landed
  __builtin_amdgcn_s_barrier();
#pragma unroll
  for (int i = 0; i < 8; ++i) {
    int g = w * 8 + i;
    ld_lds16(Ybase + (size_t)g * 2048, &SH[g * 512]);  // Y-skip tile into freed buf0
  }
  G2_COMPUTE(1);                                       // tile 7
  asm volatile("s_waitcnt vmcnt(0)" ::: "memory");     // Y landed
  __builtin_amdgcn_s_barrier();

  float wsum[4][7] = {};
#pragma unroll
  for (int j = 0; j < 16; ++j) {
    int col = j * 16 + l15;
    float bb = brel[col] + bskip[col];
#pragma unroll
    for (int r = 0; r < 4; ++r) {
      int rl = w * 16 + quad * 4 + r;
      float z = acc[j][r] + bb + bf2f(SH[rl * 256 + col]);
#pragma unroll
      for (int c = 0; c < 7; ++c) wsum[r][c] += z * Wcls[col * 7 + c];
    }
  }
#pragma unroll
  for (int o = 1; o < 16; o <<= 1)
#pragma unroll
    for (int r = 0; r < 4; ++r)
#pragma unroll
      for (int c = 0; c < 7; ++c) wsum[r][c] += __shfl_xor(wsum[r][c], o, 64);

  float lsum = 0.f;
#pragma unroll
  for (int r = 0; r < 4; ++r) {
    int row = m0 + w * 16 + quad * 4 + r;
    float o7[7], mx = -1e30f;
#pragma unroll
    for (int c = 0; c < 7; ++c) {
      o7[c] = wsum[r][c] + bcls[c];
      mx = fmaxf(mx, o7[c]);
    }
    if (l15 < 7) out[(size_t)row * 7 + l15] = o7[l15];
    float s = 0.f;
#pragma unroll
    for (int c = 0; c < 7; ++c) s += expf(o7[c] - mx);
    int lab = labels[row];
    lsum += mx + logf(s) - o7[lab];
  }
  lsum += __shfl_xor(lsum, 16, 64);
  lsum += __shfl_xor(lsum, 32, 64);
  if (lane == 0) atomicAdd(loss, lsum * (1.0f / (float)NN));
#undef G2_STAGE
#undef G2_COMPUTE
}

extern "C" void kernel_launch(void* const* d_in, const int* in_sizes, int n_in,
                              void* d_out, int out_size, void* d_ws, size_t ws_size,
                              hipStream_t stream) {
  const float* x      = (const float*)d_in[0];
  const int* speakers = (const int*)d_in[2];
  const int* labels   = (const int*)d_in[3];
  const float* Wrgcn  = (const float*)d_in[6];
  const float* Wroot  = (const float*)d_in[7];
  const float* brgcn  = (const float*)d_in[8];
  const float* Wrel   = (const float*)d_in[9];
  const float* brel   = (const float*)d_in[10];
  const float* Wgrt   = (const float*)d_in[11];
  const float* Wskip  = (const float*)d_in[12];
  const float* bskip  = (const float*)d_in[13];
  const float* Wcls   = (const float*)d_in[14];
  const float* bcls   = (const float*)d_in[15];
  float* out = (float*)d_out;
  float* loss = out + (size_t)NN * 7;

  // workspace layout (bytes) — Xbf eliminated (X read as fp32 by gemm1)
  const size_t OFF_WBIG = 0;                  //  2,097,152
  const size_t OFF_WSM  = 2097152;            //    262,144
  const size_t OFF_Y    = 2359296;            // 67,108,864  (bf16 [Y0|Y1|Yroot|Yskip])
  const size_t OFF_A2   = 69468160;           // 33,554,432  (bf16 [h|neigh])
  const size_t NEED     = 103022592;
  if (ws_size < NEED) return;

  char* ws = (char*)d_ws;
  unsigned short* WbigT = (unsigned short*)(ws + OFF_WBIG);
  unsigned short* WsmT  = (unsigned short*)(ws + OFF_WSM);
  unsigned short* Y     = (unsigned short*)(ws + OFF_Y);
  unsigned short* A2    = (unsigned short*)(ws + OFF_A2);

  diagcn_prep<<<dim3(288), dim3(256), 0, stream>>>(Wrgcn, Wroot, Wskip, Wgrt, Wrel,
                                                   WbigT, WsmT, loss);
  diagcn_gemm1<<<dim3(512), dim3(512), 0, stream>>>(x, WbigT, Y);
  diagcn_h<<<dim3(NN / 8), dim3(256), 0, stream>>>(Y, speakers, brgcn, A2);
  diagcn_neigh<<<dim3(NN / 8), dim3(256), 0, stream>>>(A2);
  diagcn_gemm2<<<dim3(512), dim3(256), 0, stream>>>(A2, WsmT, Y, Wcls, bcls, brel, bskip,
                                                    labels, out, loss);
}